// Round 6
// baseline (490.435 us; speedup 1.0000x reference)
//
#include <hip/hip_runtime.h>
#include <hip/hip_bf16.h>

typedef __hip_bfloat16 bf16;

#define ROWS 204800
#define N_INV (1.0f / 204800.0f)

// --- static device scratch (d_ws proved too small; do not touch it) ----------
__device__ float g_stats[256];            // sum1[64] sumsq1[64] sum2[32] sumsq2[32]
__device__ float g_E1_1[1000 * 64];
__device__ float g_E1_2[100 * 64];
__device__ float g_E1_3[50 * 64];
__device__ float g_U[8 * 64];
__device__ float g_Vb[64];
__device__ bf16  g_h1p[ROWS * 64];        // 26.2 MB bf16 h1_pre staging
__device__ bf16  g_h2p[ROWS * 32];        // 13.1 MB bf16 h2_pre staging

__device__ __forceinline__ int clampi(int v, int hi) {
    return v < 0 ? 0 : (v > hi ? hi : v);
}
__device__ __forceinline__ int rl_i(int v, int l) {
    return __builtin_amdgcn_readlane(v, l);
}
__device__ __forceinline__ float rl_f(float v, int l) {
    return __uint_as_float((unsigned int)__builtin_amdgcn_readlane((int)__float_as_uint(v), l));
}
__device__ __forceinline__ float b2f(unsigned short u) {
    return __uint_as_float(((unsigned int)u) << 16);
}

// ---------------------------------------------------------------------------
// Kernel A: E1_t = emb_t @ W1_t^T (t=1..3), U = cont_w @ W1_cont^T,
// Vb = b1 + sum_j cont_b[j] @ W1_cont_j^T. Block 1150 zeroes the stat block.
// ---------------------------------------------------------------------------
__global__ __launch_bounds__(64) void precompute_kernel(
    const float* __restrict__ emb1, const float* __restrict__ emb2, const float* __restrict__ emb3,
    const float* __restrict__ cont_w, const float* __restrict__ cont_b,
    const float* __restrict__ w1, const float* __restrict__ b1)
{
    int b = blockIdx.x;
    int k = threadIdx.x;
    __shared__ float row[32];

    if (b < 1150) {
        const float* tab; float* out; int i, colOff;
        if (b < 1000)      { tab = emb1; out = g_E1_1; i = b;        colOff = 32; }
        else if (b < 1100) { tab = emb2; out = g_E1_2; i = b - 1000; colOff = 64; }
        else               { tab = emb3; out = g_E1_3; i = b - 1100; colOff = 96; }
        if (k < 32) row[k] = tab[i * 32 + k];
        __syncthreads();
        const float* wr = w1 + k * 384 + colOff;
        float acc = 0.f;
        #pragma unroll
        for (int d = 0; d < 32; ++d) acc = fmaf(row[d], wr[d], acc);
        out[i * 64 + k] = acc;
    } else {
        g_stats[k]       = 0.f;
        g_stats[k + 64]  = 0.f;
        g_stats[k + 128] = 0.f;
        g_stats[k + 192] = 0.f;

        float vb = b1[k];
        #pragma unroll
        for (int j = 0; j < 8; ++j) {
            const float* wr = w1 + k * 384 + (4 + j) * 32;
            float u = 0.f;
            #pragma unroll
            for (int d = 0; d < 32; ++d) {
                float w = wr[d];
                u  = fmaf(cont_w[j * 32 + d], w, u);
                vb = fmaf(cont_b[j * 32 + d], w, vb);
            }
            g_U[j * 64 + k] = u;
        }
        g_Vb[k] = vb;
    }
}

// ---------------------------------------------------------------------------
// Phase 1: 1-deep software-pipelined gathers; readlane broadcasts (constant
// source lanes -> SGPRs, scalar gather addresses). 8 rows/wave, 6400 blocks.
// ---------------------------------------------------------------------------
__global__ __launch_bounds__(256) void phase1_kernel(
    const float* __restrict__ x,
    const float* __restrict__ emb0, const float* __restrict__ lin0,
    const float* __restrict__ emb1, const float* __restrict__ lin1,
    const float* __restrict__ emb2, const float* __restrict__ lin2,
    const float* __restrict__ emb3, const float* __restrict__ lin3,
    const float* __restrict__ cont_w, const float* __restrict__ cont_b,
    const float* __restrict__ clin_w, const float* __restrict__ clin_b,
    const float* __restrict__ fin_bias, const float* __restrict__ w1,
    float* __restrict__ fm_out)
{
    __shared__ float lsum[64], lsq[64];

    int tid  = threadIdx.x;
    int lane = tid & 63;
    int wv   = tid >> 6;
    int d    = lane & 31;
    bool lo  = lane < 32;

    if (tid < 64) { lsum[tid] = 0.f; lsq[tid] = 0.f; }
    __syncthreads();

    float w1col[32];
    {
        const float4* wr = (const float4*)(w1 + lane * 384);
        #pragma unroll
        for (int q = 0; q < 8; ++q) {
            float4 v = wr[q];
            w1col[4*q+0] = v.x; w1col[4*q+1] = v.y;
            w1col[4*q+2] = v.z; w1col[4*q+3] = v.w;
        }
    }
    float uk[8];
    #pragma unroll
    for (int j = 0; j < 8; ++j) uk[j] = g_U[j * 64 + lane];
    float vbk = g_Vb[lane];

    float p1[8], p2[8], fb = 0.f;
    if (lo) {
        #pragma unroll
        for (int j = 0; j < 8; ++j) { p1[j] = cont_w[j * 32 + d]; p2[j] = cont_b[j * 32 + d]; }
    } else {
        #pragma unroll
        for (int j = 0; j < 8; ++j) { p1[j] = clin_w[j * 32 + d]; p2[j] = clin_b[j * 32 + d]; }
        fb = fin_bias[d];
    }

    const float* T0 = lo ? emb0 : lin0;
    const float* T1 = lo ? emb1 : lin1;
    const float* T2 = lo ? emb2 : lin2;
    const float* T3 = lo ? emb3 : lin3;

    int gw   = blockIdx.x * 4 + wv;        // 0..25599
    int base = gw * 8;
    float ss = 0.f, qq = 0.f;

    // ---- prologue: stage row `base`
    float xv = (lane < 12) ? x[base * 12 + lane] : 0.f;
    int iv = (int)xv;
    int ci0 = clampi(rl_i(iv, 0), 99999);
    int ci1 = clampi(rl_i(iv, 1), 999);
    int ci2 = clampi(rl_i(iv, 2), 99);
    int ci3 = clampi(rl_i(iv, 3), 49);
    float cx[8];
    #pragma unroll
    for (int j = 0; j < 8; ++j) cx[j] = rl_f(xv, 4 + j);
    float cga = T0[ci0 * 32 + d], cgb = T1[ci1 * 32 + d];
    float cgc = T2[ci2 * 32 + d], cgd = T3[ci3 * 32 + d];
    float ct1 = g_E1_1[ci1 * 64 + lane];
    float ct2 = g_E1_2[ci2 * 64 + lane];
    float ct3 = g_E1_3[ci3 * 64 + lane];
    float xvn = (lane < 12) ? x[(base + 1) * 12 + lane] : 0.f;

    for (int it = 0; it < 8; ++it) {
        int r = base + it;

        // ---- front end for row it+1 (issues gathers; dummy idx 0 on last iter)
        int ivn = (int)xvn;
        int ni0 = clampi(rl_i(ivn, 0), 99999);
        int ni1 = clampi(rl_i(ivn, 1), 999);
        int ni2 = clampi(rl_i(ivn, 2), 99);
        int ni3 = clampi(rl_i(ivn, 3), 49);
        float nx[8];
        #pragma unroll
        for (int j = 0; j < 8; ++j) nx[j] = rl_f(xvn, 4 + j);
        float nga = T0[ni0 * 32 + d], ngb = T1[ni1 * 32 + d];
        float ngc = T2[ni2 * 32 + d], ngd = T3[ni3 * 32 + d];
        float nt1 = g_E1_1[ni1 * 64 + lane];
        float nt2 = g_E1_2[ni2 * 64 + lane];
        float nt3 = g_E1_3[ni3 * 64 + lane];
        float xv2 = (it < 6 && lane < 12) ? x[(r + 2) * 12 + lane] : 0.f;

        // ---- compute row it from staged regs
        float half_val;
        if (lo) {
            float s = (cga + cgb) + (cgc + cgd);
            float q = fmaf(cga, cga, cgb * cgb) + fmaf(cgc, cgc, cgd * cgd);
            #pragma unroll
            for (int j = 0; j < 8; ++j) {
                float ce = fmaf(cx[j], p1[j], p2[j]);
                s += ce;
                q = fmaf(ce, ce, q);
            }
            half_val = 0.5f * (s * s - q);          // interaction
        } else {
            float l = (cga + cgb) + (cgc + cgd) + fb;
            #pragma unroll
            for (int j = 0; j < 8; ++j) l = fmaf(cx[j], p1[j], l + p2[j]);
            half_val = l;                           // linear
        }
        float other = __shfl(half_val, lane | 32);
        if (lo) fm_out[r * 32 + d] = half_val + other;

        float h1 = (vbk + ct1) + (ct2 + ct3);
        #pragma unroll
        for (int j = 0; j < 8; ++j) h1 = fmaf(cx[j], uk[j], h1);
        float a0 = 0.f, a1 = 0.f, a2 = 0.f, a3 = 0.f;
        #pragma unroll
        for (int dd = 0; dd < 32; dd += 4) {
            a0 = fmaf(rl_f(cga, dd + 0), w1col[dd + 0], a0);
            a1 = fmaf(rl_f(cga, dd + 1), w1col[dd + 1], a1);
            a2 = fmaf(rl_f(cga, dd + 2), w1col[dd + 2], a2);
            a3 = fmaf(rl_f(cga, dd + 3), w1col[dd + 3], a3);
        }
        h1 += (a0 + a1) + (a2 + a3);

        g_h1p[r * 64 + lane] = __float2bfloat16(h1);
        ss += h1;
        qq = fmaf(h1, h1, qq);

        // ---- rotate pipeline
        cga = nga; cgb = ngb; cgc = ngc; cgd = ngd;
        ct1 = nt1; ct2 = nt2; ct3 = nt3;
        #pragma unroll
        for (int j = 0; j < 8; ++j) cx[j] = nx[j];
        xvn = xv2;
    }

    atomicAdd(&lsum[lane], ss);
    atomicAdd(&lsq[lane], qq);
    __syncthreads();
    if (tid < 64) {
        atomicAdd(&g_stats[tid], lsum[tid]);        // sum1
        atomicAdd(&g_stats[64 + tid], lsq[tid]);    // sumsq1
    }
}

// ---------------------------------------------------------------------------
// Phase 2: 2 rows per wave-iteration. Lane pair-loads h1 (bf16x2), BN+relu,
// intra-wave LDS broadcast of y1 (DS pipe is in-order per wave — no barrier),
// split-K across half-waves + shfl_xor combine. 16 rows/wave, 3200 blocks.
// ---------------------------------------------------------------------------
__global__ __launch_bounds__(256) void phase2_kernel(
    const float* __restrict__ w2, const float* __restrict__ b2,
    const float* __restrict__ g1, const float* __restrict__ beta1)
{
    __shared__ float y1s[4][2][64];
    __shared__ float lsum[32], lsq[32];

    int tid  = threadIdx.x;
    int lane = tid & 63;
    int wv   = tid >> 6;
    int m    = lane & 31;
    int h    = lane >> 5;

    if (tid < 32) { lsum[tid] = 0.f; lsq[tid] = 0.f; }
    __syncthreads();

    float w2h[32];
    {
        const float4* wr = (const float4*)(w2 + m * 64 + 32 * h);
        #pragma unroll
        for (int q = 0; q < 8; ++q) {
            float4 v = wr[q];
            w2h[4*q+0] = v.x; w2h[4*q+1] = v.y;
            w2h[4*q+2] = v.z; w2h[4*q+3] = v.w;
        }
    }

    // BN1 affine for the lane's channel pair (2m, 2m+1)
    float mu0 = g_stats[2*m] * N_INV;
    float va0 = g_stats[64 + 2*m] * N_INV - mu0 * mu0;
    float a10 = g1[2*m] * rsqrtf(va0 + 1e-5f);
    float c10 = beta1[2*m] - a10 * mu0;
    float mu1 = g_stats[2*m+1] * N_INV;
    float va1 = g_stats[64 + 2*m+1] * N_INV - mu1 * mu1;
    float a11 = g1[2*m+1] * rsqrtf(va1 + 1e-5f);
    float c11 = beta1[2*m+1] - a11 * mu1;
    float b2m = b2[m];

    const unsigned int* h1u = (const unsigned int*)g_h1p;
    int gw   = blockIdx.x * 4 + wv;        // 0..12799
    int base = gw * 16;
    float ss = 0.f, qq = 0.f;

    unsigned int u = h1u[base * 32 + lane];

    for (int it = 0; it < 8; ++it) {
        int r0 = base + 2 * it;
        unsigned int un = (it < 7) ? h1u[(r0 + 2) * 32 + lane] : 0u;

        float f0 = __uint_as_float(u << 16);
        float f1 = __uint_as_float(u & 0xffff0000u);
        float y0  = fmaxf(0.f, fmaf(a10, f0, c10));
        float y1v = fmaxf(0.f, fmaf(a11, f1, c11));
        *(float2*)&y1s[wv][h][2 * m] = make_float2(y0, y1v);
        __builtin_amdgcn_wave_barrier();

        float aA0 = 0.f, aA1 = 0.f, aB0 = 0.f, aB1 = 0.f;
        #pragma unroll
        for (int kq = 0; kq < 8; ++kq) {
            float4 va = *(const float4*)&y1s[wv][0][32 * h + 4 * kq];
            float4 vb = *(const float4*)&y1s[wv][1][32 * h + 4 * kq];
            aA0 = fmaf(va.x, w2h[4*kq+0], aA0);
            aA0 = fmaf(va.y, w2h[4*kq+1], aA0);
            aA1 = fmaf(va.z, w2h[4*kq+2], aA1);
            aA1 = fmaf(va.w, w2h[4*kq+3], aA1);
            aB0 = fmaf(vb.x, w2h[4*kq+0], aB0);
            aB0 = fmaf(vb.y, w2h[4*kq+1], aB0);
            aB1 = fmaf(vb.z, w2h[4*kq+2], aB1);
            aB1 = fmaf(vb.w, w2h[4*kq+3], aB1);
        }
        __builtin_amdgcn_wave_barrier();
        float pA = aA0 + aA1, pB = aB0 + aB1;
        float fA = pA + __shfl_xor(pA, 32) + b2m;
        float fB = pB + __shfl_xor(pB, 32) + b2m;

        g_h2p[r0 * 32 + lane] = __float2bfloat16(h ? fB : fA);
        ss += fA + fB;                               // double-counted; halved below
        qq = fmaf(fA, fA, fmaf(fB, fB, qq));
        u = un;
    }

    atomicAdd(&lsum[m], ss);
    atomicAdd(&lsq[m], qq);
    __syncthreads();
    if (tid < 32) {
        atomicAdd(&g_stats[128 + tid], 0.5f * lsum[tid]);  // sum2
        atomicAdd(&g_stats[160 + tid], 0.5f * lsq[tid]);   // sumsq2
    }
}

// ---------------------------------------------------------------------------
// Phase 3: 2 rows per wave-iteration (half-wave per row), y2 via intra-wave
// LDS broadcast, full-K per lane (w_out column in 32 VGPRs). 3200 blocks.
// ---------------------------------------------------------------------------
__global__ __launch_bounds__(256) void phase3_kernel(
    const float* __restrict__ w_out, const float* __restrict__ b_out,
    const float* __restrict__ g2, const float* __restrict__ beta2,
    float* __restrict__ out)   // holds FM partial on entry
{
    __shared__ float y2s[4][2][32];

    int tid  = threadIdx.x;
    int lane = tid & 63;
    int wv   = tid >> 6;
    int m    = lane & 31;
    int h    = lane >> 5;

    float wo[32];
    {
        const float4* wr = (const float4*)(w_out + m * 32);
        #pragma unroll
        for (int q = 0; q < 8; ++q) {
            float4 v = wr[q];
            wo[4*q+0] = v.x; wo[4*q+1] = v.y;
            wo[4*q+2] = v.z; wo[4*q+3] = v.w;
        }
    }

    float mu = g_stats[128 + m] * N_INV;
    float va = g_stats[160 + m] * N_INV - mu * mu;
    float a2 = g2[m] * rsqrtf(va + 1e-5f);
    float c2 = beta2[m] - a2 * mu;
    float bo = b_out[m];

    const unsigned short* h2u = (const unsigned short*)g_h2p;
    int gw   = blockIdx.x * 4 + wv;        // 0..12799
    int base = gw * 16;

    unsigned short hv = h2u[base * 32 + lane];
    float fv = out[base * 32 + lane];

    for (int it = 0; it < 8; ++it) {
        int r0 = base + 2 * it;
        unsigned short hn = (it < 7) ? h2u[(r0 + 2) * 32 + lane] : (unsigned short)0;
        float fn = (it < 7) ? out[(r0 + 2) * 32 + lane] : 0.f;

        float y2 = fmaxf(0.f, fmaf(a2, b2f(hv), c2));
        y2s[wv][h][m] = y2;
        __builtin_amdgcn_wave_barrier();

        float acc0 = 0.f, acc1 = 0.f;
        #pragma unroll
        for (int kq = 0; kq < 8; ++kq) {
            float4 v = *(const float4*)&y2s[wv][h][4 * kq];
            acc0 = fmaf(v.x, wo[4*kq+0], acc0);
            acc0 = fmaf(v.y, wo[4*kq+1], acc0);
            acc1 = fmaf(v.z, wo[4*kq+2], acc1);
            acc1 = fmaf(v.w, wo[4*kq+3], acc1);
        }
        __builtin_amdgcn_wave_barrier();
        out[r0 * 32 + lane] = fv + bo + (acc0 + acc1);
        hv = hn; fv = fn;
    }
}

// ---------------------------------------------------------------------------
extern "C" void kernel_launch(void* const* d_in, const int* in_sizes, int n_in,
                              void* d_out, int out_size, void* d_ws, size_t ws_size,
                              hipStream_t stream) {
    (void)in_sizes; (void)n_in; (void)out_size; (void)d_ws; (void)ws_size;

    // setup_inputs() dict order (emb/lin interleaved!) — all float32
    const float* x       = (const float*)d_in[0];
    const float* emb0    = (const float*)d_in[1];
    const float* lin0    = (const float*)d_in[2];
    const float* emb1    = (const float*)d_in[3];
    const float* lin1    = (const float*)d_in[4];
    const float* emb2    = (const float*)d_in[5];
    const float* lin2    = (const float*)d_in[6];
    const float* emb3    = (const float*)d_in[7];
    const float* lin3    = (const float*)d_in[8];
    const float* cont_w  = (const float*)d_in[9];
    const float* cont_b  = (const float*)d_in[10];
    const float* clin_w  = (const float*)d_in[11];
    const float* clin_b  = (const float*)d_in[12];
    const float* fin_bias= (const float*)d_in[13];
    const float* w1      = (const float*)d_in[14];
    const float* b1      = (const float*)d_in[15];
    const float* g1      = (const float*)d_in[16];
    const float* beta1   = (const float*)d_in[17];
    const float* w2      = (const float*)d_in[18];
    const float* b2      = (const float*)d_in[19];
    const float* g2      = (const float*)d_in[20];
    const float* beta2   = (const float*)d_in[21];
    const float* w_out   = (const float*)d_in[22];
    const float* b_out   = (const float*)d_in[23];

    float* outp = (float*)d_out;               // also stages the FM partial

    hipLaunchKernelGGL(precompute_kernel, dim3(1151), dim3(64), 0, stream,
                       emb1, emb2, emb3, cont_w, cont_b, w1, b1);

    hipLaunchKernelGGL(phase1_kernel, dim3(6400), dim3(256), 0, stream,
                       x, emb0, lin0, emb1, lin1, emb2, lin2, emb3, lin3,
                       cont_w, cont_b, clin_w, clin_b, fin_bias, w1,
                       outp);

    hipLaunchKernelGGL(phase2_kernel, dim3(3200), dim3(256), 0, stream,
                       w2, b2, g1, beta1);

    hipLaunchKernelGGL(phase3_kernel, dim3(3200), dim3(256), 0, stream,
                       w_out, b_out, g2, beta2, outp);
}